// Round 6
// baseline (2661.078 us; speedup 1.0000x reference)
//
#include <hip/hip_runtime.h>
#include <math.h>
#include <stdint.h>

namespace {
constexpr int INN   = 512;          // visible input rows (act[:512] == x always)
constexpr int LAY   = 2048;
constexpr int DYN   = LAY - INN;    // 1536 dynamic elements: act[512..2048)
constexpr int NITER = 512;
constexpr int NBLK  = 64;
constexpr int TPB   = 256;          // 4 waves
constexpr int WVS   = TPB / 64;     // 4
constexpr int RPW   = 6;            // rows per wave
constexpr int RPB   = WVS * RPW;    // 24 rows per block; 64*24 = 1536; 3 whole
                                    // 64B lines per block -> no cross-XCD false sharing
constexpr int KC    = DYN / 64;     // 24 k-chunks per lane (dynamic columns)
constexpr int KX    = INN / 64;     // 8 k-chunks (x columns, precomputed)
constexpr int EPT   = DYN / TPB;    // 6 tagged elements polled per thread
constexpr float EPS = 1e-12f;

__device__ __forceinline__ uint64_t pack(float v, uint32_t tag) {
  union { float f; uint32_t u; } c; c.f = v;
  return (uint64_t)c.u | ((uint64_t)tag << 32);
}
__device__ __forceinline__ float val_of(uint64_t p) {
  union { uint32_t u; float f; } c; c.u = (uint32_t)p; return c.f;
}
// Cross-XCD visibility via CACHED path + explicit fences (not UC atomics):
// release = s_waitcnt + buffer_wbl2 sc1 (push dirty lines to MALL)
// acquire = buffer_inv sc1 (invalidate stale L1/L2 so next loads refetch MALL)
__device__ __forceinline__ void fence_rel() {
  __builtin_amdgcn_fence(__ATOMIC_RELEASE, "agent");
}
__device__ __forceinline__ void fence_acq() {
  __builtin_amdgcn_fence(__ATOMIC_ACQUIRE, "agent");
}

// Persistent kernel, 512 iterations in one launch. Same geometry/algebra as
// round 4 (validated: absmax 0.0). ONLY the exchange memory path changed:
// plain cached 8-byte stores/loads (single-instruction -> value+tag never
// tear) + explicit agent fences, replacing UC-bypass atomics. Tag
// self-validation makes inter-word ordering unnecessary; fences provide
// freshness (writeback/invalidate). L2 invalidation is free here: W, x, c_r
// live in registers, act in LDS — nothing hot is in L2.
// Overwrite safety unchanged: a block stores tag t+1 only after block-wide
// consumption of tag t, so tag t+2 (clobbering t) implies all consumed t.
__global__ __launch_bounds__(TPB) void bm_persistent(
    const float* __restrict__ x, const float* __restrict__ W,
    uint64_t* __restrict__ buf0, uint64_t* __restrict__ buf1,
    float* __restrict__ out) {
  __shared__ float s_act[DYN];
  __shared__ float s_red[WVS];
  const int tid = threadIdx.x;
  const int wv  = tid >> 6;
  const int ln  = tid & 63;
  const int blk = blockIdx.x;
  const int r0  = INN + blk * RPB + wv * RPW;   // this wave's 6 rows (>=512)

  // ---- one-time: W[r, 512:2048] into registers (6 x 24 = 144 VGPR) ----
  float w[RPW][KC];
  const float* __restrict__ Wr = W + (size_t)r0 * LAY;
#pragma unroll
  for (int r = 0; r < RPW; ++r)
#pragma unroll
    for (int i = 0; i < KC; ++i)
      w[r][i] = Wr[(size_t)r * LAY + INN + ln + 64 * i];

  // ---- one-time: c_r = W[r,:512] @ x  (fully reduced; all lanes hold sum) ----
  float xv[KX];
#pragma unroll
  for (int i = 0; i < KX; ++i) xv[i] = x[ln + 64 * i];
  float c[RPW];
#pragma unroll
  for (int r = 0; r < RPW; ++r) {
    float cc = 0.f;
#pragma unroll
    for (int i = 0; i < KX; ++i)
      cc = fmaf(Wr[(size_t)r * LAY + ln + 64 * i], xv[i], cc);
#pragma unroll
    for (int o = 1; o < 64; o <<= 1) cc += __shfl_xor(cc, o, 64);
    c[r] = cc;
  }

  // ---- bootstrap: act(1) = relu(c_r) (h(0)=0, y(0)=0), tag 1 -> buf1 ----
  if (ln == 0) {
#pragma unroll
    for (int r = 0; r < RPW; ++r)
      buf1[r0 - INN + r] = pack(fmaxf(c[r], 0.f), 1u);
  }
  fence_rel();                              // push bootstrap lines to MALL

  float myv[EPT];
  float inv = 0.f;
  for (int t = 1;; ++t) {
    if (t == NITER && blk != 0) return;     // non-0 blocks already stored tag 512
    const uint64_t* __restrict__ rb = (t & 1) ? buf1 : buf0;

    // ---- poll act(t): cached loads; on miss-tag, invalidate & refetch ----
    uint64_t pv[EPT];
    for (;;) {
      bool ok = true;
#pragma unroll
      for (int j = 0; j < EPT; ++j)
        pv[j] = rb[tid + TPB * j];
#pragma unroll
      for (int j = 0; j < EPT; ++j)
        ok &= ((uint32_t)(pv[j] >> 32) == (uint32_t)t);
      if (ok) break;
      fence_acq();                          // drop stale L1/L2 copies, repoll
    }

    // ---- stage to LDS + sum-of-squares of hidden part (j>=2 <=> k>=1024) ----
    float ss = 0.f;
#pragma unroll
    for (int j = 0; j < EPT; ++j) {
      const float v = val_of(pv[j]);
      myv[j] = v;
      s_act[tid + TPB * j] = v;
      if (j >= 2) ss = fmaf(v, v, ss);
    }
#pragma unroll
    for (int o = 1; o < 64; o <<= 1) ss += __shfl_xor(ss, o, 64);
    if (ln == 0) s_red[wv] = ss;
    __syncthreads();                        // poll done block-wide; s_act/s_red ready
    inv = 1.0f / fmaxf(sqrtf(s_red[0] + s_red[1] + s_red[2] + s_red[3]), EPS);

    if (t == NITER) break;                  // blk 0 falls through to output

    // ---- matvec: y_r = c_r + W[r,512:1024]@a_y + inv * W[r,1024:2048]@h ----
    float aa[RPW], bb[RPW];
#pragma unroll
    for (int r = 0; r < RPW; ++r) { aa[r] = 0.f; bb[r] = 0.f; }
#pragma unroll
    for (int i = 0; i < 8; ++i) {           // p in [0,512): y-region
      const float a = s_act[ln + 64 * i];
#pragma unroll
      for (int r = 0; r < RPW; ++r) aa[r] = fmaf(w[r][i], a, aa[r]);
    }
#pragma unroll
    for (int i = 8; i < KC; ++i) {          // p in [512,1536): hidden region
      const float a = s_act[ln + 64 * i];
#pragma unroll
      for (int r = 0; r < RPW; ++r) bb[r] = fmaf(w[r][i], a, bb[r]);
    }
    // reduce per-lane partials FIRST; add fully-reduced c_r AFTER.
    float y[RPW];
#pragma unroll
    for (int r = 0; r < RPW; ++r) y[r] = fmaf(inv, bb[r], aa[r]);
#pragma unroll
    for (int o = 1; o < 64; o <<= 1) {
#pragma unroll
      for (int r = 0; r < RPW; ++r) y[r] += __shfl_xor(y[r], o, 64);
    }
#pragma unroll
    for (int r = 0; r < RPW; ++r) y[r] += c[r];
    __syncthreads();                        // WAR: LDS reads done before next stage

    if (ln == 0) {
      uint64_t* __restrict__ wb = ((t + 1) & 1) ? buf1 : buf0;
#pragma unroll
      for (int r = 0; r < RPW; ++r)
        wb[r0 - INN + r] = pack(fmaxf(y[r], 0.f), (uint32_t)(t + 1));
    }
    fence_rel();                            // s_waitcnt + wbl2: push lines to MALL
  }

  // ---- blk 0: write final output ----
  out[tid]       = x[tid];
  out[tid + TPB] = x[tid + TPB];
#pragma unroll
  for (int j = 0; j < EPT; ++j)
    out[INN + tid + TPB * j] = (j < 2) ? myv[j] : myv[j] * inv;
}
} // namespace

extern "C" void kernel_launch(void* const* d_in, const int* in_sizes, int n_in,
                              void* d_out, int out_size, void* d_ws, size_t ws_size,
                              hipStream_t stream) {
  const float* x = (const float*)d_in[0];
  // d_in[1] (y) only enters the reference as zeros_like -> unused.
  const float* W = (const float*)d_in[2];
  float* out = (float*)d_out;

  uint64_t* buf0 = (uint64_t*)d_ws;
  uint64_t* buf1 = buf0 + DYN;

  // Invalidate stale tags (0xFFFFFFFF matches no t in 1..512) — needed on the
  // first call and between graph replays (harness does not re-poison d_ws).
  hipMemsetAsync(d_ws, 0xFF, (size_t)2 * DYN * sizeof(uint64_t), stream);

  bm_persistent<<<dim3(NBLK), dim3(TPB), 0, stream>>>(x, W, buf0, buf1, out);
}

// Round 8
// 2144.181 us; speedup vs baseline: 1.2411x; 1.2411x over previous
//
#include <hip/hip_runtime.h>
#include <math.h>
#include <stdint.h>

namespace {
constexpr int INN   = 512;          // visible rows: act[:512] == x always
constexpr int LAY   = 2048;
constexpr int DYN   = LAY - INN;    // 1536 dynamic elements act[512..2048)
constexpr int NITER = 512;
constexpr int NBLK  = 64;
constexpr int TPB   = 256;          // 4 waves
constexpr int WVS   = TPB / 64;     // 4
constexpr int RPW   = 6;            // rows per wave
constexpr int RPB   = WVS * RPW;    // 24 rows/block; 64*24 = 1536
constexpr int KC    = DYN / 64;     // 24 dynamic k-chunks per lane
constexpr int KX    = INN / 64;     // 8 x-col k-chunks (precomputed)
constexpr int EPT   = DYN / TPB;    // 6 data elements per thread
constexpr int VALVE = 100000;       // leader-poll passes before graceful abort
constexpr float EPS = 1e-12f;

// Proven medium (R2-R4, absmax 0.0): agent-scope UC ops, served at MALL,
// cross-XCD coherent, no fences needed.
__device__ __forceinline__ void ag_storef(float* p, float v) {
  __hip_atomic_store(p, v, __ATOMIC_RELAXED, __HIP_MEMORY_SCOPE_AGENT);
}
__device__ __forceinline__ float ag_loadf(const float* p) {
  return __hip_atomic_load(p, __ATOMIC_RELAXED, __HIP_MEMORY_SCOPE_AGENT);
}
__device__ __forceinline__ uint32_t ag_loadu(const uint32_t* p) {
  return __hip_atomic_load(p, __ATOMIC_RELAXED, __HIP_MEMORY_SCOPE_AGENT);
}

// Counter-epoch persistent kernel. Per iteration:
//  [1] leader polls counter >= NBLK*t  -> barrier        (signal)
//  [2] one-shot batched read of act(t), stage LDS        (data, touched once)
//  [3] inv-norm; matvec; y = relu(c + a + inv*b)
//  [4] lane0 stores y (UC);  __syncthreads() drains (vmcnt(0)) = release
//  [5] tid0 atomicAdd(counter, 1)
// Overwrite safety: a block writes parity (t+1)&1 at [4] only after [1]
// proved counter>=NBLK*t, i.e. every block finished [5]@t-1... inductively
// every block's reads of that parity (at t-1) completed. Same invariant
// validated in R3/R4.
__global__ __launch_bounds__(TPB, 1) void bm_ctr(
    const float* __restrict__ x, const float* __restrict__ W,
    float* __restrict__ f0, float* __restrict__ f1,
    uint32_t* __restrict__ ctr, float* __restrict__ out) {
  __shared__ float s_act[DYN];
  __shared__ float s_red[WVS];
  __shared__ int s_go;
  const int tid = threadIdx.x;
  const int wv  = tid >> 6;
  const int ln  = tid & 63;
  const int blk = blockIdx.x;
  const int r0  = INN + blk * RPB + wv * RPW;   // this wave's 6 rows

  // ---- one-time: W[r,512:2048] into registers (6x24 = 144 VGPR) ----
  float w[RPW][KC];
  const float* __restrict__ Wr = W + (size_t)r0 * LAY;
#pragma unroll
  for (int r = 0; r < RPW; ++r)
#pragma unroll
    for (int i = 0; i < KC; ++i)
      w[r][i] = Wr[(size_t)r * LAY + INN + ln + 64 * i];

  // ---- one-time: c_r = W[r,:512]@x (fully reduced; added AFTER lane-reduce) ----
  float c[RPW];
  {
    float xv[KX];
#pragma unroll
    for (int i = 0; i < KX; ++i) xv[i] = x[ln + 64 * i];
#pragma unroll
    for (int r = 0; r < RPW; ++r) {
      float cc = 0.f;
#pragma unroll
      for (int i = 0; i < KX; ++i)
        cc = fmaf(Wr[(size_t)r * LAY + ln + 64 * i], xv[i], cc);
#pragma unroll
      for (int o = 1; o < 64; o <<= 1) cc += __shfl_xor(cc, o, 64);
      c[r] = cc;
    }
  }

  // ---- bootstrap: act(1) = relu(c_r) -> f1; drain; count ----
  if (ln == 0) {
#pragma unroll
    for (int r = 0; r < RPW; ++r)
      ag_storef(&f1[r0 - INN + r], fmaxf(c[r], 0.f));
  }
  __syncthreads();                       // emits s_waitcnt vmcnt(0): stores ACKed
  if (tid == 0) atomicAdd(ctr, 1u);      // device-scope release-after-drain

  float myv[EPT];
  float inv = 0.f;

  for (int t = 1;; ++t) {
    if (t == NITER && blk != 0) return;  // they counted t=NITER at end of t-1

    // [1] signal wait: single leader polls one line
    if (tid == 0) {
      const uint32_t target = (uint32_t)(NBLK * t);
      int go = 1, p = 0;
      while (ag_loadu(ctr) < target) {
        if (++p > VALVE) { go = -1; break; }
      }
      s_go = go;
    }
    __syncthreads();
    if (s_go < 0) return;                // graceful abort (never a hang)

    // [2] one-shot data read + LDS stage + hidden sum-of-squares (j>=2 <=> e>=512)
    const float* __restrict__ rbuf = (t & 1) ? f1 : f0;
    float ss = 0.f;
#pragma unroll
    for (int j = 0; j < EPT; ++j) {
      const float v = ag_loadf(&rbuf[tid + TPB * j]);
      myv[j] = v;
      s_act[tid + TPB * j] = v;
      if (j >= 2) ss = fmaf(v, v, ss);
    }
#pragma unroll
    for (int o = 1; o < 64; o <<= 1) ss += __shfl_xor(ss, o, 64);
    if (ln == 0) s_red[wv] = ss;
    __syncthreads();
    inv = 1.0f / fmaxf(sqrtf(s_red[0] + s_red[1] + s_red[2] + s_red[3]), EPS);

    if (t == NITER) break;               // only blk 0 reaches

    // [3] matvec: y = relu(c + W[:,y-region]@a + inv * W[:,hidden]@h)
    float aa[RPW], bb[RPW];
#pragma unroll
    for (int r = 0; r < RPW; ++r) { aa[r] = 0.f; bb[r] = 0.f; }
#pragma unroll
    for (int i = 0; i < 8; ++i) {        // dyn cols [0,512): y-region
      const float a = s_act[ln + 64 * i];
#pragma unroll
      for (int r = 0; r < RPW; ++r) aa[r] = fmaf(w[r][i], a, aa[r]);
    }
#pragma unroll
    for (int i = 8; i < KC; ++i) {       // dyn cols [512,1536): hidden
      const float a = s_act[ln + 64 * i];
#pragma unroll
      for (int r = 0; r < RPW; ++r) bb[r] = fmaf(w[r][i], a, bb[r]);
    }
    float y[RPW];
#pragma unroll
    for (int r = 0; r < RPW; ++r) y[r] = fmaf(inv, bb[r], aa[r]);
#pragma unroll
    for (int o = 1; o < 64; o <<= 1) {
#pragma unroll
      for (int r = 0; r < RPW; ++r) y[r] += __shfl_xor(y[r], o, 64);
    }
#pragma unroll
    for (int r = 0; r < RPW; ++r) y[r] = fmaxf(y[r] + c[r], 0.f);  // c AFTER reduce

    // [4] publish act(t+1); [5] count
    float* __restrict__ wbuf = ((t + 1) & 1) ? f1 : f0;
    if (ln == 0) {
#pragma unroll
      for (int r = 0; r < RPW; ++r)
        ag_storef(&wbuf[r0 - INN + r], y[r]);
    }
    __syncthreads();                     // drains UC stores + WAR guard on s_act
    if (tid == 0) atomicAdd(ctr, 1u);
  }

  // ---- blk 0: final output (act(512); hidden part normalized) ----
  out[tid]       = x[tid];
  out[tid + TPB] = x[tid + TPB];
#pragma unroll
  for (int j = 0; j < EPT; ++j)
    out[INN + tid + TPB * j] = (j < 2) ? myv[j] : myv[j] * inv;
}
} // namespace

extern "C" void kernel_launch(void* const* d_in, const int* in_sizes, int n_in,
                              void* d_out, int out_size, void* d_ws, size_t ws_size,
                              hipStream_t stream) {
  const float* x = (const float*)d_in[0];
  // d_in[1] (y) only enters the reference as zeros_like -> unused.
  const float* W = (const float*)d_in[2];
  float* out = (float*)d_out;

  float* f0 = (float*)d_ws;
  float* f1 = f0 + DYN;
  uint32_t* ctr = (uint32_t*)((char*)d_ws + ((size_t)2 * DYN * sizeof(float) + 255 & ~255ull));

  // Counter must start at 0 every call (incl. graph replays). Data buffers
  // need no init: they are read only after the counter proves them written.
  hipMemsetAsync(ctr, 0, 64, stream);

  bm_ctr<<<dim3(NBLK), dim3(TPB), 0, stream>>>(x, W, f0, f1, ctr, out);
}

// Round 9
// 2078.441 us; speedup vs baseline: 1.2803x; 1.0316x over previous
//
#include <hip/hip_runtime.h>
#include <math.h>
#include <stdint.h>

namespace {
constexpr int INN   = 512;          // visible rows: act[:512] == x always
constexpr int LAY   = 2048;
constexpr int DYN   = LAY - INN;    // 1536 dynamic elements act[512..2048)
constexpr int NITER = 512;
constexpr int NBLK  = 64;
constexpr int TPB   = 256;          // 4 waves
constexpr int WVS   = TPB / 64;     // 4
constexpr int RPW   = 6;            // rows per wave
constexpr int RPB   = WVS * RPW;    // 24 rows/block; 64*24 = 1536
constexpr int KC    = DYN / 64;     // 24 dynamic k-chunks per lane
constexpr int KX    = INN / 64;     // 8 x-col k-chunks (precomputed)
constexpr int EPT   = DYN / TPB;    // 6 (fallback kernel)
constexpr int NW2   = DYN / 2;      // 768 float2 words per data slot
constexpr int VALVE = 200000;       // flag-poll passes before graceful abort
constexpr float EPS = 1e-12f;

__device__ __forceinline__ uint64_t pack2(float a, float b) {
  union { float f[2]; uint64_t u; } c; c.f[0] = a; c.f[1] = b; return c.u;
}
// Proven UC/MALL primitives (R2-R4, R7: absmax 0.0)
__device__ __forceinline__ void ag_store64(void* p, uint64_t v) {
  __hip_atomic_store((uint64_t*)p, v, __ATOMIC_RELAXED, __HIP_MEMORY_SCOPE_AGENT);
}
__device__ __forceinline__ uint64_t ag_load64(const void* p) {
  return __hip_atomic_load((const uint64_t*)p, __ATOMIC_RELAXED, __HIP_MEMORY_SCOPE_AGENT);
}
__device__ __forceinline__ void ag_storeu(uint32_t* p, uint32_t v) {
  __hip_atomic_store(p, v, __ATOMIC_RELAXED, __HIP_MEMORY_SCOPE_AGENT);
}
__device__ __forceinline__ uint32_t ag_loadu(const uint32_t* p) {
  return __hip_atomic_load(p, __ATOMIC_RELAXED, __HIP_MEMORY_SCOPE_AGENT);
}

// ---------------- primary kernel: flag-signaled rotating one-shot buffers ----
// Per iteration t:
//  [1] wave0 UC-polls 64 per-block flags (parity t&1) until all == t
//  [2] barrier; ALL threads cold-read data[t] with plain CACHED float2 loads
//      (fresh address each t -> L2 miss -> served by MALL, which holds the
//      UC-stored truth; zero UC transactions on the 6 KB payload)
//  [3] inv-norm; matvec; y = relu(c + a + inv*b)
//  [4] lane0s UC-store 3 float2 words into data[t+1]
//  [5] __syncthreads() (drains vmcnt: all data stores ACKed at MALL — the
//      R7-proven release) ; tid0 UC-stores flag[t+1 parity][blk] = t+1
// Flag parity reuse safety: block writes flag t+1 only after seeing all
// flags == t, which inductively implies every block finished polling t-1.
// Data slots are write-once/read-once at distinct addresses (no reuse at all).
__global__ __launch_bounds__(TPB) void bm_rot(
    const float* __restrict__ x, const float* __restrict__ W,
    float2* __restrict__ data, uint32_t* __restrict__ flags,
    float* __restrict__ out) {
  __shared__ float s_act[DYN];
  __shared__ float s_red[WVS];
  __shared__ int s_go;
  const int tid = threadIdx.x;
  const int wv  = tid >> 6;
  const int ln  = tid & 63;
  const int blk = blockIdx.x;
  const int r0  = INN + blk * RPB + wv * RPW;   // this wave's 6 rows
  const int wb  = 12 * blk + 3 * wv;            // this wave's 3 float2 words

  // ---- one-time: W[r,512:2048] into registers ----
  float w[RPW][KC];
  const float* __restrict__ Wr = W + (size_t)r0 * LAY;
#pragma unroll
  for (int r = 0; r < RPW; ++r)
#pragma unroll
    for (int i = 0; i < KC; ++i)
      w[r][i] = Wr[(size_t)r * LAY + INN + ln + 64 * i];

  // ---- one-time: c_r = W[r,:512]@x (fully reduced; added AFTER lane-reduce) ----
  float c[RPW];
  {
    float xv[KX];
#pragma unroll
    for (int i = 0; i < KX; ++i) xv[i] = x[ln + 64 * i];
#pragma unroll
    for (int r = 0; r < RPW; ++r) {
      float cc = 0.f;
#pragma unroll
      for (int i = 0; i < KX; ++i)
        cc = fmaf(Wr[(size_t)r * LAY + ln + 64 * i], xv[i], cc);
#pragma unroll
      for (int o = 1; o < 64; o <<= 1) cc += __shfl_xor(cc, o, 64);
      c[r] = cc;
    }
  }

  // ---- bootstrap: act(1) = relu(c_r) -> data[1]; drain; flag ----
  if (ln == 0) {
    float2* d1 = data + (size_t)1 * NW2;
#pragma unroll
    for (int k = 0; k < 3; ++k)
      ag_store64(&d1[wb + k],
                 pack2(fmaxf(c[2 * k], 0.f), fmaxf(c[2 * k + 1], 0.f)));
  }
  __syncthreads();                       // vmcnt(0): data stores ACKed at MALL
  if (tid == 0) ag_storeu(&flags[64 + blk], 1u);   // parity(1)=1

  float2 v0, v1, v2;
  float inv = 0.f;

  for (int t = 1;; ++t) {
    if (t == NITER && blk != 0) return;  // they already stored data[512]+flag

    // [1] flag wait: wave0 polls 64 flags (tiny UC traffic)
    if (wv == 0) {
      const uint32_t* f = flags + (size_t)(t & 1) * 64;
      int ok = 1, p = 0;
      while (!__all(ag_loadu(&f[ln]) == (uint32_t)t)) {
        if (++p > VALVE) { ok = 0; break; }
      }
      if (ln == 0) s_go = ok;
    }
    __syncthreads();
    if (!s_go) return;                   // graceful abort (never a hang)

    // [2] cold cached read of data[t] (coalesced float2) + stage + hidden ss
    const float2* __restrict__ dt = data + (size_t)t * NW2;
    v0 = dt[tid]; v1 = dt[tid + 256]; v2 = dt[tid + 512];
    float2* s2 = (float2*)s_act;
    s2[tid] = v0; s2[tid + 256] = v1; s2[tid + 512] = v2;
    // elements: v0 -> [0,512) y-region; v1 -> [512,1024), v2 -> [1024,1536) hidden
    float ss = v1.x * v1.x;
    ss = fmaf(v1.y, v1.y, ss);
    ss = fmaf(v2.x, v2.x, ss);
    ss = fmaf(v2.y, v2.y, ss);
#pragma unroll
    for (int o = 1; o < 64; o <<= 1) ss += __shfl_xor(ss, o, 64);
    if (ln == 0) s_red[wv] = ss;
    __syncthreads();                     // s_act + s_red published
    inv = 1.0f / fmaxf(sqrtf(s_red[0] + s_red[1] + s_red[2] + s_red[3]), EPS);

    if (t == NITER) break;               // only blk 0 reaches

    // [3] matvec: y = relu(c + W[:,y]@a + inv * W[:,h]@h)
    float aa[RPW], bb[RPW];
#pragma unroll
    for (int r = 0; r < RPW; ++r) { aa[r] = 0.f; bb[r] = 0.f; }
#pragma unroll
    for (int i = 0; i < 8; ++i) {        // dyn cols [0,512): y-region
      const float a = s_act[ln + 64 * i];
#pragma unroll
      for (int r = 0; r < RPW; ++r) aa[r] = fmaf(w[r][i], a, aa[r]);
    }
#pragma unroll
    for (int i = 8; i < KC; ++i) {       // dyn cols [512,1536): hidden
      const float a = s_act[ln + 64 * i];
#pragma unroll
      for (int r = 0; r < RPW; ++r) bb[r] = fmaf(w[r][i], a, bb[r]);
    }
    float y[RPW];
#pragma unroll
    for (int r = 0; r < RPW; ++r) y[r] = fmaf(inv, bb[r], aa[r]);
#pragma unroll
    for (int o = 1; o < 64; o <<= 1) {
#pragma unroll
      for (int r = 0; r < RPW; ++r) y[r] += __shfl_xor(y[r], o, 64);
    }
#pragma unroll
    for (int r = 0; r < RPW; ++r) y[r] = fmaxf(y[r] + c[r], 0.f);  // c AFTER reduce

    // [4] publish data[t+1] (UC stores, write-once address)
    if (ln == 0) {
      float2* dn = data + (size_t)(t + 1) * NW2;
#pragma unroll
      for (int k = 0; k < 3; ++k)
        ag_store64(&dn[wb + k], pack2(y[2 * k], y[2 * k + 1]));
    }
    // [5] drain (vmcnt(0)) + covers s_act WAR; then signal
    __syncthreads();
    if (tid == 0) ag_storeu(&flags[(size_t)((t + 1) & 1) * 64 + blk],
                            (uint32_t)(t + 1));
  }

  // ---- blk 0: final output (hidden part normalized) ----
  out[tid]       = x[tid];
  out[tid + 256] = x[tid + 256];
  out[INN + 2 * tid]            = v0.x;
  out[INN + 2 * tid + 1]        = v0.y;
  out[INN + 512 + 2 * tid]      = v1.x * inv;
  out[INN + 512 + 2 * tid + 1]  = v1.y * inv;
  out[INN + 1024 + 2 * tid]     = v2.x * inv;
  out[INN + 1024 + 2 * tid + 1] = v2.y * inv;
}

// ---------------- fallback kernel: R4 verbatim (proven, 1826 us) ------------
__device__ __forceinline__ uint64_t packtag(float v, uint32_t tag) {
  union { float f; uint32_t u; } c; c.f = v;
  return (uint64_t)c.u | ((uint64_t)tag << 32);
}
__device__ __forceinline__ float val_of(uint64_t p) {
  union { uint32_t u; float f; } c; c.u = (uint32_t)p; return c.f;
}
__global__ __launch_bounds__(TPB) void bm_tag(
    const float* __restrict__ x, const float* __restrict__ W,
    uint64_t* __restrict__ buf0, uint64_t* __restrict__ buf1,
    float* __restrict__ out) {
  __shared__ float s_act[DYN];
  __shared__ float s_red[WVS];
  const int tid = threadIdx.x, wv = tid >> 6, ln = tid & 63, blk = blockIdx.x;
  const int r0 = INN + blk * RPB + wv * RPW;
  float w[RPW][KC];
  const float* __restrict__ Wr = W + (size_t)r0 * LAY;
#pragma unroll
  for (int r = 0; r < RPW; ++r)
#pragma unroll
    for (int i = 0; i < KC; ++i)
      w[r][i] = Wr[(size_t)r * LAY + INN + ln + 64 * i];
  float c[RPW];
  {
    float xv[KX];
#pragma unroll
    for (int i = 0; i < KX; ++i) xv[i] = x[ln + 64 * i];
#pragma unroll
    for (int r = 0; r < RPW; ++r) {
      float cc = 0.f;
#pragma unroll
      for (int i = 0; i < KX; ++i)
        cc = fmaf(Wr[(size_t)r * LAY + ln + 64 * i], xv[i], cc);
#pragma unroll
      for (int o = 1; o < 64; o <<= 1) cc += __shfl_xor(cc, o, 64);
      c[r] = cc;
    }
  }
  if (ln == 0) {
#pragma unroll
    for (int r = 0; r < RPW; ++r)
      ag_store64(&buf1[r0 - INN + r], packtag(fmaxf(c[r], 0.f), 1u));
  }
  float myv[EPT]; float inv = 0.f;
  for (int t = 1;; ++t) {
    if (t == NITER && blk != 0) return;
    uint64_t* rb = (t & 1) ? buf1 : buf0;
    uint64_t pv[EPT];
    for (;;) {
      bool ok = true;
#pragma unroll
      for (int j = 0; j < EPT; ++j) pv[j] = ag_load64(&rb[tid + TPB * j]);
#pragma unroll
      for (int j = 0; j < EPT; ++j) ok &= ((uint32_t)(pv[j] >> 32) == (uint32_t)t);
      if (ok) break;
    }
    float ss = 0.f;
#pragma unroll
    for (int j = 0; j < EPT; ++j) {
      const float v = val_of(pv[j]);
      myv[j] = v; s_act[tid + TPB * j] = v;
      if (j >= 2) ss = fmaf(v, v, ss);
    }
#pragma unroll
    for (int o = 1; o < 64; o <<= 1) ss += __shfl_xor(ss, o, 64);
    if (ln == 0) s_red[wv] = ss;
    __syncthreads();
    inv = 1.0f / fmaxf(sqrtf(s_red[0] + s_red[1] + s_red[2] + s_red[3]), EPS);
    if (t == NITER) break;
    float aa[RPW], bb[RPW];
#pragma unroll
    for (int r = 0; r < RPW; ++r) { aa[r] = 0.f; bb[r] = 0.f; }
#pragma unroll
    for (int i = 0; i < 8; ++i) {
      const float a = s_act[ln + 64 * i];
#pragma unroll
      for (int r = 0; r < RPW; ++r) aa[r] = fmaf(w[r][i], a, aa[r]);
    }
#pragma unroll
    for (int i = 8; i < KC; ++i) {
      const float a = s_act[ln + 64 * i];
#pragma unroll
      for (int r = 0; r < RPW; ++r) bb[r] = fmaf(w[r][i], a, bb[r]);
    }
    float y[RPW];
#pragma unroll
    for (int r = 0; r < RPW; ++r) y[r] = fmaf(inv, bb[r], aa[r]);
#pragma unroll
    for (int o = 1; o < 64; o <<= 1) {
#pragma unroll
      for (int r = 0; r < RPW; ++r) y[r] += __shfl_xor(y[r], o, 64);
    }
#pragma unroll
    for (int r = 0; r < RPW; ++r) y[r] = fmaxf(y[r] + c[r], 0.f);
    __syncthreads();
    if (ln == 0) {
      uint64_t* wbuf = ((t + 1) & 1) ? buf1 : buf0;
#pragma unroll
      for (int r = 0; r < RPW; ++r)
        ag_store64(&wbuf[r0 - INN + r], packtag(y[r], (uint32_t)(t + 1)));
    }
  }
  out[tid] = x[tid]; out[tid + TPB] = x[tid + TPB];
#pragma unroll
  for (int j = 0; j < EPT; ++j)
    out[INN + tid + TPB * j] = (j < 2) ? myv[j] : myv[j] * inv;
}
} // namespace

extern "C" void kernel_launch(void* const* d_in, const int* in_sizes, int n_in,
                              void* d_out, int out_size, void* d_ws, size_t ws_size,
                              hipStream_t stream) {
  const float* x = (const float*)d_in[0];
  // d_in[1] (y) only enters the reference as zeros_like -> unused.
  const float* W = (const float*)d_in[2];
  float* out = (float*)d_out;

  const size_t data_bytes = (size_t)(NITER + 1) * NW2 * sizeof(float2); // ~3.15 MB
  const size_t need = data_bytes + 2 * 64 * sizeof(uint32_t);

  if (ws_size >= need) {
    float2*   data  = (float2*)d_ws;
    uint32_t* flags = (uint32_t*)((char*)d_ws + data_bytes);
    // Flags must start !=1..512 each call (incl. replays). Data slots need no
    // reset: write-once addresses gated by flags; replay-stale values are
    // bitwise identical (deterministic) and the first timed replay's reads
    // are flag-gated behind this replay's own UC stores.
    hipMemsetAsync(flags, 0, 2 * 64 * sizeof(uint32_t), stream);
    bm_rot<<<dim3(NBLK), dim3(TPB), 0, stream>>>(x, W, data, flags, out);
  } else {
    // Proven R4 path.
    uint64_t* buf0 = (uint64_t*)d_ws;
    uint64_t* buf1 = buf0 + DYN;
    hipMemsetAsync(d_ws, 0xFF, (size_t)2 * DYN * sizeof(uint64_t), stream);
    bm_tag<<<dim3(NBLK), dim3(TPB), 0, stream>>>(x, W, buf0, buf1, out);
  }
}